// Round 5
// baseline (175.603 us; speedup 1.0000x reference)
//
#include <hip/hip_runtime.h>
#include <hip/hip_bf16.h>
#include <float.h>

#define BB   32
#define PP   16384
#define NOBJ 50
#define NCLS 21
#define PBLK 64   // blocks of 256 priors per image (P/256)
#define NBLK (BB * PBLK)

// ---------------- workspace layout ----------------
// [0]       u64   bestprior[BB*NOBJ]     (12800 B) packed (iou_bits<<32)|(~p)
// [12800]   int   n_pos[BB]              (128 B)
// [12928]   double accum[3]              (24 B)  0:conf_pos 1:loc_sum 2:hard_neg
// [16384]   float overlap[BB*PP]         (2 MB)
// [+2MB]    int   objfor[BB*PP]          (2 MB)
// [+4MB]    float neg[BB*PP]             (2 MB)
// [+6MB]    double pc_conf[NBLK]         (16 KB)
// [..]      double pc_loc[NBLK]          (16 KB)
// [..]      int    pc_npos[NBLK]         (8 KB)

// per-prior argmax over objects — pure registers, boxes via uniform s_load
__global__ __launch_bounds__(256) void k_overlap(
    const float* __restrict__ boxes, const float* __restrict__ priors,
    float* __restrict__ overlap, int* __restrict__ objfor)
{
#pragma clang fp contract(off)
    const int b  = (int)blockIdx.x >> 6;
    const int p0 = ((int)blockIdx.x & 63) << 8;
    const int t  = (int)threadIdx.x;
    const int p  = p0 + t;

    const float4* gbox = reinterpret_cast<const float4*>(boxes) + b * NOBJ;

    float4 pc = reinterpret_cast<const float4*>(priors)[p];
    float hx = pc.z / 2.0f, hy = pc.w / 2.0f;
    float px0 = pc.x - hx, py0 = pc.y - hy;
    float px1 = pc.x + hx, py1 = pc.y + hy;
    float areab = (px1 - px0) * (py1 - py0);

    float best = -1.0f; int bestn = 0;
#pragma unroll 10
    for (int n = 0; n < NOBJ; ++n) {
        float4 bx = gbox[n];                         // uniform -> s_load_dwordx4
        float ltx = fmaxf(bx.x, px0), lty = fmaxf(bx.y, py0);
        float rbx = fminf(bx.z, px1), rby = fminf(bx.w, py1);
        float dx = fmaxf(rbx - ltx, 0.0f);
        float dy = fmaxf(rby - lty, 0.0f);
        float inter = dx * dy;
        float sarea = (bx.z - bx.x) * (bx.w - bx.y);
        float iou = __fdividef(inter, (sarea + areab) - inter);
        if (iou > best) { best = iou; bestn = n; }   // first-max wins (strict >)
    }
    overlap[b * PP + p] = best;
    objfor[b * PP + p]  = bestn;
}

// per-object argmax over priors — one wave per (image, object-pair), pure
// registers, plain store (no atomics, no init needed)
__global__ __launch_bounds__(64) void k_bestp(
    const float* __restrict__ boxes, const float* __restrict__ priors,
    unsigned long long* __restrict__ bestprior)
{
#pragma clang fp contract(off)
    const int b  = (int)blockIdx.x / 25;
    const int n0 = ((int)blockIdx.x % 25) * 2;
    const int l  = (int)threadIdx.x;
    const float4* gpri = reinterpret_cast<const float4*>(priors);

    unsigned long long bk[2] = {0ull, 0ull};
    float ax0[2], ay0[2], ax1[2], ay1[2], aarea[2];
#pragma unroll
    for (int k = 0; k < 2; ++k) {
        float4 bx = reinterpret_cast<const float4*>(boxes)[b * NOBJ + n0 + k];
        ax0[k] = bx.x; ay0[k] = bx.y; ax1[k] = bx.z; ay1[k] = bx.w;
        aarea[k] = (bx.z - bx.x) * (bx.w - bx.y);
    }

#pragma unroll 4
    for (int j = 0; j < PP / 64; ++j) {
        int p = l + 64 * j;
        float4 pc = gpri[p];
        float hx = pc.z / 2.0f, hy = pc.w / 2.0f;
        float px0 = pc.x - hx, py0 = pc.y - hy;
        float px1 = pc.x + hx, py1 = pc.y + hy;
        float areab = (px1 - px0) * (py1 - py0);
        unsigned inv = 0xFFFFFFFFu - (unsigned)p;
#pragma unroll
        for (int k = 0; k < 2; ++k) {
            float ltx = fmaxf(ax0[k], px0), lty = fmaxf(ay0[k], py0);
            float rbx = fminf(ax1[k], px1), rby = fminf(ay1[k], py1);
            float dx = fmaxf(rbx - ltx, 0.0f);
            float dy = fmaxf(rby - lty, 0.0f);
            float inter = dx * dy;
            float iou = __fdividef(inter, (aarea[k] + areab) - inter);
            unsigned long long key =
                ((unsigned long long)__float_as_uint(iou) << 32) |
                (unsigned long long)inv;
            if (key > bk[k]) bk[k] = key;   // ties: larger inv = smaller p
        }
    }
#pragma unroll
    for (int k = 0; k < 2; ++k) {
        unsigned long long v = bk[k];
        for (int o = 32; o > 0; o >>= 1) {
            unsigned long long other = __shfl_down(v, o, 64);
            if (other > v) v = other;
        }
        if (l == 0) bestprior[b * NOBJ + n0 + k] = v;
    }
}

__global__ void k_force(const unsigned long long* __restrict__ bestprior,
                        float* __restrict__ overlap, int* __restrict__ objfor) {
    int b = (int)threadIdx.x;
    if (b >= BB) return;
    for (int n = 0; n < NOBJ; ++n) {                 // ascending n -> last wins
        unsigned long long pk = bestprior[b * NOBJ + n];
        int p = (int)(0xFFFFFFFFu - (unsigned)(pk & 0xFFFFFFFFull));
        objfor[b * PP + p]  = n;
        overlap[b * PP + p] = 1.0f;
    }
}

__global__ __launch_bounds__(256) void k_main(
    const float* __restrict__ locs, const float* __restrict__ scores,
    const float* __restrict__ boxes, const int* __restrict__ labels,
    const float* __restrict__ priors, const float* __restrict__ overlap,
    const int* __restrict__ objfor, float* __restrict__ neg,
    double* __restrict__ pc_conf, double* __restrict__ pc_loc,
    int* __restrict__ pc_npos)
{
#pragma clang fp contract(off)
    const int b   = (int)blockIdx.x >> 6;
    const int p0  = ((int)blockIdx.x & 63) << 8;
    const int t   = (int)threadIdx.x;
    const int p   = p0 + t;
    const int idx = b * PP + p;

    // stage 256x21 scores tile via coalesced float4 loads (21504 B, 16B-aligned)
    __shared__ float sls[256 * NCLS];
    __shared__ double sconf[4], sloc[4];
    __shared__ int    snp[4];
    {
        const float4* gsc = reinterpret_cast<const float4*>(
            scores + (size_t)(b * PP + p0) * NCLS);
        float4* dls = reinterpret_cast<float4*>(sls);
#pragma unroll
        for (int i = 0; i < 6; ++i) {
            int j = i * 256 + t;
            if (j < (256 * NCLS) / 4) dls[j] = gsc[j];
        }
    }
    __syncthreads();

    const int   n = objfor[idx];
    const float v = overlap[idx];
    int lbl = labels[b * NOBJ + n];
    if (v < 0.5f) lbl = 0;
    const bool pos = (lbl != 0);

    float locl1 = 0.0f;
    if (pos) {
        float4 bx = reinterpret_cast<const float4*>(boxes)[b * NOBJ + n];
        float4 pr = reinterpret_cast<const float4*>(priors)[p];
        float cx = (bx.x + bx.z) / 2.0f;
        float cy = (bx.y + bx.w) / 2.0f;
        float w  = bx.z - bx.x, h = bx.w - bx.y;
        float gx = (cx - pr.x) / (pr.z / 10.0f);
        float gy = (cy - pr.y) / (pr.w / 10.0f);
        float gw = logf(w / pr.z) * 5.0f;
        float gh = logf(h / pr.w) * 5.0f;
        float4 pl = reinterpret_cast<const float4*>(locs)[idx];
        locl1 = fabsf(pl.x - gx) + fabsf(pl.y - gy) +
                fabsf(pl.z - gw) + fabsf(pl.w - gh);
    }

    // cross-entropy via log-softmax over 21 classes (from LDS; stride 21 vs
    // 32 banks is coprime -> 2-way aliasing only, free)
    float x[NCLS];
    float m = -FLT_MAX;
#pragma unroll
    for (int c = 0; c < NCLS; ++c) { x[c] = sls[t * NCLS + c]; m = fmaxf(m, x[c]); }
    float tgt = 0.0f;
#pragma unroll
    for (int c = 0; c < NCLS; ++c) tgt = (c == lbl) ? x[c] : tgt;
    float s = 0.0f;
#pragma unroll
    for (int c = 0; c < NCLS; ++c) s += expf(x[c] - m);
    float ce = (logf(s) + m) - tgt;

    neg[idx] = pos ? 0.0f : ce;

    // wave reductions -> per-block partials (NO global atomics)
    float cp = pos ? ce : 0.0f;
    unsigned long long bal = __ballot(pos);
    float s1 = cp, s2 = locl1;
    for (int o = 32; o > 0; o >>= 1) {
        s1 += __shfl_down(s1, o, 64);
        s2 += __shfl_down(s2, o, 64);
    }
    if ((t & 63) == 0) {
        int w = t >> 6;
        sconf[w] = (double)s1;
        sloc[w]  = (double)s2;
        snp[w]   = (int)__popcll(bal);
    }
    __syncthreads();
    if (t == 0) {
        pc_conf[blockIdx.x] = sconf[0] + sconf[1] + sconf[2] + sconf[3];
        pc_loc[blockIdx.x]  = sloc[0] + sloc[1] + sloc[2] + sloc[3];
        pc_npos[blockIdx.x] = snp[0] + snp[1] + snp[2] + snp[3];
    }
}

// blocks 0..BB-1: n_pos[b] = sum of that image's 64 block partials
// block BB: accum[0]=sum pc_conf, accum[1]=sum pc_loc, accum[2]=0 (pre-topk)
__global__ __launch_bounds__(256) void k_reduce(
    const double* __restrict__ pc_conf, const double* __restrict__ pc_loc,
    const int* __restrict__ pc_npos, int* __restrict__ n_pos,
    double* __restrict__ accum)
{
    const int t = (int)threadIdx.x;
    if ((int)blockIdx.x < BB) {
        const int b = (int)blockIdx.x;
        int v = (t < PBLK) ? pc_npos[b * PBLK + t] : 0;
        for (int o = 32; o > 0; o >>= 1) v += __shfl_down(v, o, 64);
        if (t == 0) n_pos[b] = v;
    } else {
        __shared__ double sa[4], sb[4];
        double a = 0.0, c = 0.0;
        for (int i = t; i < NBLK; i += 256) { a += pc_conf[i]; c += pc_loc[i]; }
        for (int o = 32; o > 0; o >>= 1) {
            a += __shfl_down(a, o, 64);
            c += __shfl_down(c, o, 64);
        }
        if ((t & 63) == 0) { sa[t >> 6] = a; sb[t >> 6] = c; }
        __syncthreads();
        if (t == 0) {
            accum[0] = sa[0] + sa[1] + sa[2] + sa[3];
            accum[1] = sb[0] + sb[1] + sb[2] + sb[3];
            accum[2] = 0.0;                          // reset before k_topk adds
        }
    }
}

// exact sum of top-K of neg[b,:] via 4x8-bit radix select (ce >= 0 so
// float bit pattern is order-preserving as uint). All passes run from LDS.
__global__ __launch_bounds__(1024) void k_topk(
    const float* __restrict__ neg, const int* __restrict__ n_pos,
    double* __restrict__ accum)
{
    const int b = (int)blockIdx.x;
    const int t = (int)threadIdx.x;
    const int wid = t >> 6;

    __shared__ float sval[PP];                 // 64 KB staged image
    __shared__ unsigned shist[16 * 257];       // per-wave padded histograms
    __shared__ unsigned scomb[256];
    __shared__ unsigned s_bb, s_above;
    __shared__ float swave[16];

    // stage neg[b,:] coalesced
    {
        const float4* g = reinterpret_cast<const float4*>(neg + (size_t)b * PP);
        float4* d = reinterpret_cast<float4*>(sval);
#pragma unroll
        for (int i = 0; i < PP / 4 / 1024; ++i)
            d[i * 1024 + t] = g[i * 1024 + t];
    }

    long long K = 3LL * (long long)n_pos[b];
    if (K > PP) K = PP;
    unsigned remaining = (unsigned)K;
    unsigned prefix = 0, mask = 0;
    float mySum = 0.0f;
    __syncthreads();

    for (int shift = 24; shift >= 0; shift -= 8) {
        for (int i = t; i < 16 * 257; i += 1024) shist[i] = 0;
        __syncthreads();
#pragma unroll
        for (int i = 0; i < PP / 1024; ++i) {
            unsigned u = __float_as_uint(sval[i * 1024 + t]);
            if ((u & mask) == prefix)
                atomicAdd(&shist[wid * 257 + ((u >> shift) & 255u)], 1u);
        }
        __syncthreads();
        if (t < 256) {
            unsigned c = 0;
#pragma unroll
            for (int w = 0; w < 16; ++w) c += shist[w * 257 + t];
            scomb[t] = c;
        }
        __syncthreads();
        if (t == 0) {
            unsigned cum = 0, bb = 0, above = 0;
            for (int bin = 255; bin >= 0; --bin) {
                unsigned c = scomb[bin];
                if (cum + c >= remaining) { bb = (unsigned)bin; above = cum; break; }
                cum += c;
            }
            s_bb = bb; s_above = above;
        }
        __syncthreads();
        unsigned bb = s_bb;
#pragma unroll
        for (int i = 0; i < PP / 1024; ++i) {
            unsigned u = __float_as_uint(sval[i * 1024 + t]);
            if ((u & mask) == prefix && ((u >> shift) & 255u) > bb)
                mySum += __uint_as_float(u);
        }
        remaining -= s_above;
        prefix |= bb << shift;
        mask   |= 255u << shift;
        __syncthreads();
    }

    float s = mySum;
    for (int o = 32; o > 0; o >>= 1) s += __shfl_down(s, o, 64);
    if ((t & 63) == 0) swave[wid] = s;
    __syncthreads();
    if (t == 0) {
        float tot = 0.0f;
        for (int w = 0; w < 16; ++w) tot += swave[w];
        if (remaining) tot += (float)remaining * __uint_as_float(prefix);
        atomicAdd(&accum[2], (double)tot);   // 32 blocks total: negligible
    }
}

__global__ void k_final(const int* __restrict__ n_pos,
                        const double* __restrict__ accum,
                        float* __restrict__ out) {
    if (threadIdx.x == 0 && blockIdx.x == 0) {
        int tot = 0;
        for (int b = 0; b < BB; ++b) tot += n_pos[b];
        double npt  = (double)tot;
        double conf = (accum[0] + accum[2]) / npt;
        double loc  = accum[1] / (npt * 4.0);
        out[0] = (float)(conf + loc);
    }
}

extern "C" void kernel_launch(void* const* d_in, const int* in_sizes, int n_in,
                              void* d_out, int out_size, void* d_ws, size_t ws_size,
                              hipStream_t stream) {
    const float* locs   = (const float*)d_in[0];
    const float* scores = (const float*)d_in[1];
    const float* boxes  = (const float*)d_in[2];
    const int*   labels = (const int*)d_in[3];
    const float* priors = (const float*)d_in[4];

    char* ws = (char*)d_ws;
    unsigned long long* bestprior = (unsigned long long*)ws;
    int*    n_pos   = (int*)(ws + 12800);
    double* accum   = (double*)(ws + 12928);
    float*  overlap = (float*)(ws + 16384);
    int*    objfor  = (int*)(ws + 16384 + (size_t)BB * PP * 4);
    float*  neg     = (float*)(ws + 16384 + (size_t)BB * PP * 8);
    char*   ppart   = ws + 16384 + (size_t)BB * PP * 12;
    double* pc_conf = (double*)ppart;
    double* pc_loc  = (double*)(ppart + NBLK * 8);
    int*    pc_npos = (int*)(ppart + NBLK * 16);
    float*  out     = (float*)d_out;

    hipLaunchKernelGGL(k_overlap, dim3(NBLK),      dim3(256),  0, stream,
                       boxes, priors, overlap, objfor);
    hipLaunchKernelGGL(k_bestp,   dim3(BB * 25),   dim3(64),   0, stream,
                       boxes, priors, bestprior);
    hipLaunchKernelGGL(k_force,   dim3(1),         dim3(64),   0, stream,
                       bestprior, overlap, objfor);
    hipLaunchKernelGGL(k_main,    dim3(NBLK),      dim3(256),  0, stream,
                       locs, scores, boxes, labels, priors, overlap, objfor,
                       neg, pc_conf, pc_loc, pc_npos);
    hipLaunchKernelGGL(k_reduce,  dim3(BB + 1),    dim3(256),  0, stream,
                       pc_conf, pc_loc, pc_npos, n_pos, accum);
    hipLaunchKernelGGL(k_topk,    dim3(BB),        dim3(1024), 0, stream,
                       neg, n_pos, accum);
    hipLaunchKernelGGL(k_final,   dim3(1),         dim3(64),   0, stream,
                       n_pos, accum, out);
}

// Round 6
// 98.906 us; speedup vs baseline: 1.7755x; 1.7755x over previous
//
#include <hip/hip_runtime.h>
#include <hip/hip_bf16.h>
#include <float.h>

#define BB   32
#define PP   16384
#define NOBJ 50
#define NCLS 21
#define PBLK 64   // blocks of 256 priors per image (P/256)
#define NBLK (BB * PBLK)

// ---------------- workspace layout ----------------
// [0]       u64   bestprior[BB*NOBJ]     (12800 B) packed (iou_bits<<32)|(~p)
// [12800]   int   n_pos[BB]              (128 B)
// [12928]   double accum[3]              (24 B)  0:conf_pos 1:loc_sum 2:hard_neg
// [16384]   float overlap[BB*PP]         (2 MB)
// [+2MB]    int   objfor[BB*PP]          (2 MB)
// [+4MB]    float neg[BB*PP]             (2 MB)
// [+6MB]    double pc_conf[NBLK]         (16 KB)
// [..]      double pc_loc[NBLK]          (16 KB)
// [..]      int    pc_npos[NBLK]         (8 KB)

__global__ void k_init(unsigned long long* __restrict__ bestprior) {
    int i = blockIdx.x * 256 + threadIdx.x;
    if (i < BB * NOBJ) bestprior[i] = 0ull;   // any real key (iou>=0) beats 0
}

// per-prior argmax over objects — pure registers, boxes via uniform s_load
__global__ __launch_bounds__(256) void k_overlap(
    const float* __restrict__ boxes, const float* __restrict__ priors,
    float* __restrict__ overlap, int* __restrict__ objfor)
{
#pragma clang fp contract(off)
    const int b  = (int)blockIdx.x >> 6;
    const int p0 = ((int)blockIdx.x & 63) << 8;
    const int t  = (int)threadIdx.x;
    const int p  = p0 + t;

    const float4* gbox = reinterpret_cast<const float4*>(boxes) + b * NOBJ;

    float4 pc = reinterpret_cast<const float4*>(priors)[p];
    float hx = pc.z / 2.0f, hy = pc.w / 2.0f;
    float px0 = pc.x - hx, py0 = pc.y - hy;
    float px1 = pc.x + hx, py1 = pc.y + hy;
    float areab = (px1 - px0) * (py1 - py0);

    float best = -1.0f; int bestn = 0;
#pragma unroll 10
    for (int n = 0; n < NOBJ; ++n) {
        float4 bx = gbox[n];                         // uniform -> s_load_dwordx4
        float ltx = fmaxf(bx.x, px0), lty = fmaxf(bx.y, py0);
        float rbx = fminf(bx.z, px1), rby = fminf(bx.w, py1);
        float dx = fmaxf(rbx - ltx, 0.0f);
        float dy = fmaxf(rby - lty, 0.0f);
        float inter = dx * dy;
        float sarea = (bx.z - bx.x) * (bx.w - bx.y);
        float iou = __fdividef(inter, (sarea + areab) - inter);
        if (iou > best) { best = iou; bestn = n; }   // first-max wins (strict >)
    }
    overlap[b * PP + p] = best;
    objfor[b * PP + p]  = bestn;
}

// per-object argmax over priors — 8 objects x 4096-prior chunk per block,
// register-resident keys, one wave-reduce at the end, global atomicMax
__global__ __launch_bounds__(256) void k_bestp(
    const float* __restrict__ boxes, const float* __restrict__ priors,
    unsigned long long* __restrict__ bestprior)
{
#pragma clang fp contract(off)
    const int b     = (int)blockIdx.x / 28;
    const int r     = (int)blockIdx.x % 28;
    const int n0    = (r >> 2) * 8;
    const int pbase = (r & 3) << 12;
    const int t     = (int)threadIdx.x;
    const float4* gpri = reinterpret_cast<const float4*>(priors);

    __shared__ unsigned long long sbest[8];
    if (t < 8) sbest[t] = 0ull;

    float ax0[8], ay0[8], ax1[8], ay1[8], aarea[8];
#pragma unroll
    for (int k = 0; k < 8; ++k) {
        int nn = n0 + k; if (nn >= NOBJ) nn = NOBJ - 1;   // clamp (discarded later)
        float4 bx = reinterpret_cast<const float4*>(boxes)[b * NOBJ + nn];
        ax0[k] = bx.x; ay0[k] = bx.y; ax1[k] = bx.z; ay1[k] = bx.w;
        aarea[k] = (bx.z - bx.x) * (bx.w - bx.y);
    }

    unsigned long long bk[8];
#pragma unroll
    for (int k = 0; k < 8; ++k) bk[k] = 0ull;

#pragma unroll 2
    for (int j = 0; j < 16; ++j) {
        int p = pbase + t + (j << 8);
        float4 pc = gpri[p];
        float hx = pc.z / 2.0f, hy = pc.w / 2.0f;
        float px0 = pc.x - hx, py0 = pc.y - hy;
        float px1 = pc.x + hx, py1 = pc.y + hy;
        float areab = (px1 - px0) * (py1 - py0);
        unsigned inv = 0xFFFFFFFFu - (unsigned)p;
#pragma unroll
        for (int k = 0; k < 8; ++k) {
            float ltx = fmaxf(ax0[k], px0), lty = fmaxf(ay0[k], py0);
            float rbx = fminf(ax1[k], px1), rby = fminf(ay1[k], py1);
            float dx = fmaxf(rbx - ltx, 0.0f);
            float dy = fmaxf(rby - lty, 0.0f);
            float inter = dx * dy;
            float iou = __fdividef(inter, (aarea[k] + areab) - inter);
            unsigned long long key =
                ((unsigned long long)__float_as_uint(iou) << 32) |
                (unsigned long long)inv;
            if (key > bk[k]) bk[k] = key;   // ties: larger inv = smaller p
        }
    }
    __syncthreads();                         // sbest init visible
#pragma unroll
    for (int k = 0; k < 8; ++k) {
        unsigned long long v = bk[k];
        for (int o = 32; o > 0; o >>= 1) {
            unsigned long long other = __shfl_down(v, o, 64);
            if (other > v) v = other;
        }
        if ((t & 63) == 0) atomicMax(&sbest[k], v);
    }
    __syncthreads();
    if (t < 8 && n0 + t < NOBJ)
        atomicMax(&bestprior[b * NOBJ + n0 + t], sbest[t]);
}

__global__ void k_force(const unsigned long long* __restrict__ bestprior,
                        float* __restrict__ overlap, int* __restrict__ objfor) {
    int b = (int)threadIdx.x;
    if (b >= BB) return;
    for (int n = 0; n < NOBJ; ++n) {                 // ascending n -> last wins
        unsigned long long pk = bestprior[b * NOBJ + n];
        int p = (int)(0xFFFFFFFFu - (unsigned)(pk & 0xFFFFFFFFull));
        objfor[b * PP + p]  = n;
        overlap[b * PP + p] = 1.0f;
    }
}

__global__ __launch_bounds__(256) void k_main(
    const float* __restrict__ locs, const float* __restrict__ scores,
    const float* __restrict__ boxes, const int* __restrict__ labels,
    const float* __restrict__ priors, const float* __restrict__ overlap,
    const int* __restrict__ objfor, float* __restrict__ neg,
    double* __restrict__ pc_conf, double* __restrict__ pc_loc,
    int* __restrict__ pc_npos)
{
#pragma clang fp contract(off)
    const int b   = (int)blockIdx.x >> 6;
    const int p0  = ((int)blockIdx.x & 63) << 8;
    const int t   = (int)threadIdx.x;
    const int p   = p0 + t;
    const int idx = b * PP + p;

    // stage 256x21 scores tile via coalesced float4 loads (21504 B, 16B-aligned)
    __shared__ float sls[256 * NCLS];
    __shared__ double sconf[4], sloc[4];
    __shared__ int    snp[4];
    {
        const float4* gsc = reinterpret_cast<const float4*>(
            scores + (size_t)(b * PP + p0) * NCLS);
        float4* dls = reinterpret_cast<float4*>(sls);
#pragma unroll
        for (int i = 0; i < 6; ++i) {
            int j = i * 256 + t;
            if (j < (256 * NCLS) / 4) dls[j] = gsc[j];
        }
    }
    __syncthreads();

    const int   n = objfor[idx];
    const float v = overlap[idx];
    int lbl = labels[b * NOBJ + n];
    if (v < 0.5f) lbl = 0;
    const bool pos = (lbl != 0);

    float locl1 = 0.0f;
    if (pos) {
        float4 bx = reinterpret_cast<const float4*>(boxes)[b * NOBJ + n];
        float4 pr = reinterpret_cast<const float4*>(priors)[p];
        float cx = (bx.x + bx.z) / 2.0f;
        float cy = (bx.y + bx.w) / 2.0f;
        float w  = bx.z - bx.x, h = bx.w - bx.y;
        float gx = (cx - pr.x) / (pr.z / 10.0f);
        float gy = (cy - pr.y) / (pr.w / 10.0f);
        float gw = logf(w / pr.z) * 5.0f;
        float gh = logf(h / pr.w) * 5.0f;
        float4 pl = reinterpret_cast<const float4*>(locs)[idx];
        locl1 = fabsf(pl.x - gx) + fabsf(pl.y - gy) +
                fabsf(pl.z - gw) + fabsf(pl.w - gh);
    }

    // cross-entropy via log-softmax over 21 classes (from LDS)
    float x[NCLS];
    float m = -FLT_MAX;
#pragma unroll
    for (int c = 0; c < NCLS; ++c) { x[c] = sls[t * NCLS + c]; m = fmaxf(m, x[c]); }
    float tgt = 0.0f;
#pragma unroll
    for (int c = 0; c < NCLS; ++c) tgt = (c == lbl) ? x[c] : tgt;
    float s = 0.0f;
#pragma unroll
    for (int c = 0; c < NCLS; ++c) s += expf(x[c] - m);
    float ce = (logf(s) + m) - tgt;

    neg[idx] = pos ? 0.0f : ce;

    // wave reductions -> per-block partials (NO global atomics)
    float cp = pos ? ce : 0.0f;
    unsigned long long bal = __ballot(pos);
    float s1 = cp, s2 = locl1;
    for (int o = 32; o > 0; o >>= 1) {
        s1 += __shfl_down(s1, o, 64);
        s2 += __shfl_down(s2, o, 64);
    }
    if ((t & 63) == 0) {
        int w = t >> 6;
        sconf[w] = (double)s1;
        sloc[w]  = (double)s2;
        snp[w]   = (int)__popcll(bal);
    }
    __syncthreads();
    if (t == 0) {
        pc_conf[blockIdx.x] = sconf[0] + sconf[1] + sconf[2] + sconf[3];
        pc_loc[blockIdx.x]  = sloc[0] + sloc[1] + sloc[2] + sloc[3];
        pc_npos[blockIdx.x] = snp[0] + snp[1] + snp[2] + snp[3];
    }
}

// blocks 0..BB-1: n_pos[b] = sum of that image's 64 block partials
// block BB: accum[0]=sum pc_conf, accum[1]=sum pc_loc, accum[2]=0 (pre-topk)
__global__ __launch_bounds__(256) void k_reduce(
    const double* __restrict__ pc_conf, const double* __restrict__ pc_loc,
    const int* __restrict__ pc_npos, int* __restrict__ n_pos,
    double* __restrict__ accum)
{
    const int t = (int)threadIdx.x;
    if ((int)blockIdx.x < BB) {
        const int b = (int)blockIdx.x;
        int v = (t < PBLK) ? pc_npos[b * PBLK + t] : 0;
        for (int o = 32; o > 0; o >>= 1) v += __shfl_down(v, o, 64);
        if (t == 0) n_pos[b] = v;
    } else {
        __shared__ double sa[4], sb[4];
        double a = 0.0, c = 0.0;
        for (int i = t; i < NBLK; i += 256) { a += pc_conf[i]; c += pc_loc[i]; }
        for (int o = 32; o > 0; o >>= 1) {
            a += __shfl_down(a, o, 64);
            c += __shfl_down(c, o, 64);
        }
        if ((t & 63) == 0) { sa[t >> 6] = a; sb[t >> 6] = c; }
        __syncthreads();
        if (t == 0) {
            accum[0] = sa[0] + sa[1] + sa[2] + sa[3];
            accum[1] = sb[0] + sb[1] + sb[2] + sb[3];
            accum[2] = 0.0;                          // reset before k_topk adds
        }
    }
}

// exact top-K sum via 4x8-bit radix select; values register-resident,
// per-LANE histogram copies (stride 257 -> equal bins = 2 lanes/bank, free),
// parallel suffix-scan bin selection. ce >= 0 so float bits are monotone.
__global__ __launch_bounds__(1024) void k_topk(
    const float* __restrict__ neg, const int* __restrict__ n_pos,
    double* __restrict__ accum)
{
    const int b    = (int)blockIdx.x;
    const int t    = (int)threadIdx.x;
    const int lane = t & 63;
    const int wid  = t >> 6;

    __shared__ unsigned hist[64 * 257];        // per-lane copies, padded
    __shared__ unsigned ssuf[256];
    __shared__ unsigned s_bb, s_above;
    __shared__ float swave[16];

    // each thread owns 16 values in registers (one coalesced sweep)
    float v[16];
    {
        const float4* g = reinterpret_cast<const float4*>(neg + (size_t)b * PP);
#pragma unroll
        for (int i = 0; i < 4; ++i) {
            float4 q = g[i * 1024 + t];
            v[i*4+0] = q.x; v[i*4+1] = q.y; v[i*4+2] = q.z; v[i*4+3] = q.w;
        }
    }

    long long K = 3LL * (long long)n_pos[b];
    if (K > PP) K = PP;
    unsigned remaining = (unsigned)K;
    unsigned prefix = 0, mask = 0;
    float mySum = 0.0f;

    for (int shift = 24; shift >= 0; shift -= 8) {
        for (int i = t; i < 64 * 257; i += 1024) hist[i] = 0;
        __syncthreads();
        unsigned* h = hist + lane * 257;
#pragma unroll
        for (int i = 0; i < 16; ++i) {
            unsigned u = __float_as_uint(v[i]);
            if ((u & mask) == prefix) atomicAdd(&h[(u >> shift) & 255u], 1u);
        }
        __syncthreads();
        // combine 64 copies -> own-count in reg + ssuf
        unsigned cnt = 0;
        if (t < 256) {
#pragma unroll
            for (int w = 0; w < 64; ++w) cnt += hist[w * 257 + t];
            ssuf[t] = cnt;
        }
        __syncthreads();
        // inclusive suffix sum over 256 bins (Hillis-Steele)
        for (int off = 1; off < 256; off <<= 1) {
            unsigned add = 0;
            if (t < 256 && t + off < 256) add = ssuf[t + off];
            __syncthreads();
            if (t < 256) ssuf[t] += add;
            __syncthreads();
        }
        if (t < 256) {
            unsigned suf = ssuf[t];
            if (suf >= remaining && suf - cnt < remaining) {
                s_bb = (unsigned)t; s_above = suf - cnt;
            }
        }
        __syncthreads();
        unsigned bb = s_bb;
#pragma unroll
        for (int i = 0; i < 16; ++i) {
            unsigned u = __float_as_uint(v[i]);
            if ((u & mask) == prefix && ((u >> shift) & 255u) > bb)
                mySum += v[i];
        }
        remaining -= s_above;
        prefix |= bb << shift;
        mask   |= 255u << shift;
        __syncthreads();
    }

    float s = mySum;
    for (int o = 32; o > 0; o >>= 1) s += __shfl_down(s, o, 64);
    if ((t & 63) == 0) swave[wid] = s;
    __syncthreads();
    if (t == 0) {
        float tot = 0.0f;
        for (int w = 0; w < 16; ++w) tot += swave[w];
        if (remaining) tot += (float)remaining * __uint_as_float(prefix);
        atomicAdd(&accum[2], (double)tot);   // 32 blocks total: negligible
    }
}

__global__ void k_final(const int* __restrict__ n_pos,
                        const double* __restrict__ accum,
                        float* __restrict__ out) {
    if (threadIdx.x == 0 && blockIdx.x == 0) {
        int tot = 0;
        for (int b = 0; b < BB; ++b) tot += n_pos[b];
        double npt  = (double)tot;
        double conf = (accum[0] + accum[2]) / npt;
        double loc  = accum[1] / (npt * 4.0);
        out[0] = (float)(conf + loc);
    }
}

extern "C" void kernel_launch(void* const* d_in, const int* in_sizes, int n_in,
                              void* d_out, int out_size, void* d_ws, size_t ws_size,
                              hipStream_t stream) {
    const float* locs   = (const float*)d_in[0];
    const float* scores = (const float*)d_in[1];
    const float* boxes  = (const float*)d_in[2];
    const int*   labels = (const int*)d_in[3];
    const float* priors = (const float*)d_in[4];

    char* ws = (char*)d_ws;
    unsigned long long* bestprior = (unsigned long long*)ws;
    int*    n_pos   = (int*)(ws + 12800);
    double* accum   = (double*)(ws + 12928);
    float*  overlap = (float*)(ws + 16384);
    int*    objfor  = (int*)(ws + 16384 + (size_t)BB * PP * 4);
    float*  neg     = (float*)(ws + 16384 + (size_t)BB * PP * 8);
    char*   ppart   = ws + 16384 + (size_t)BB * PP * 12;
    double* pc_conf = (double*)ppart;
    double* pc_loc  = (double*)(ppart + NBLK * 8);
    int*    pc_npos = (int*)(ppart + NBLK * 16);
    float*  out     = (float*)d_out;

    hipLaunchKernelGGL(k_init,    dim3(7),         dim3(256),  0, stream,
                       bestprior);
    hipLaunchKernelGGL(k_overlap, dim3(NBLK),      dim3(256),  0, stream,
                       boxes, priors, overlap, objfor);
    hipLaunchKernelGGL(k_bestp,   dim3(BB * 28),   dim3(256),  0, stream,
                       boxes, priors, bestprior);
    hipLaunchKernelGGL(k_force,   dim3(1),         dim3(64),   0, stream,
                       bestprior, overlap, objfor);
    hipLaunchKernelGGL(k_main,    dim3(NBLK),      dim3(256),  0, stream,
                       locs, scores, boxes, labels, priors, overlap, objfor,
                       neg, pc_conf, pc_loc, pc_npos);
    hipLaunchKernelGGL(k_reduce,  dim3(BB + 1),    dim3(256),  0, stream,
                       pc_conf, pc_loc, pc_npos, n_pos, accum);
    hipLaunchKernelGGL(k_topk,    dim3(BB),        dim3(1024), 0, stream,
                       neg, n_pos, accum);
    hipLaunchKernelGGL(k_final,   dim3(1),         dim3(64),   0, stream,
                       n_pos, accum, out);
}

// Round 7
// 86.213 us; speedup vs baseline: 2.0369x; 1.1472x over previous
//
#include <hip/hip_runtime.h>
#include <hip/hip_bf16.h>
#include <float.h>

#define BB   32
#define PP   16384
#define NOBJ 50
#define NCLS 21
#define PBLK 64   // blocks of 256 priors per image (P/256)
#define NBLK (BB * PBLK)

// ---------------- workspace layout ----------------
// [0]      u64    bp_part[4][BB*NOBJ]  (51200 B)  per-chunk packed keys
// [51200]  double pc_conf[NBLK]        (16 KB)
// [67584]  double pc_loc[NBLK]         (16 KB)
// [83968]  int    pc_npos[NBLK]        (8 KB)
// [92160]  double hard[BB]             (256 B)
// [131072] float  neg[BB*PP]           (2 MB)

// per-object argmax over priors — 8 objects x 4096-prior chunk per block,
// register-resident keys, wave-reduce, PLAIN per-chunk store (no atomics)
__global__ __launch_bounds__(256) void k_bestp(
    const float* __restrict__ boxes, const float* __restrict__ priors,
    unsigned long long* __restrict__ bp_part)
{
#pragma clang fp contract(off)
    const int b     = (int)blockIdx.x / 28;
    const int r     = (int)blockIdx.x % 28;
    const int n0    = (r >> 2) * 8;
    const int chunk = r & 3;
    const int pbase = chunk << 12;
    const int t     = (int)threadIdx.x;
    const float4* gpri = reinterpret_cast<const float4*>(priors);

    __shared__ unsigned long long sbest[8];
    if (t < 8) sbest[t] = 0ull;

    float ax0[8], ay0[8], ax1[8], ay1[8], aarea[8];
#pragma unroll
    for (int k = 0; k < 8; ++k) {
        int nn = n0 + k; if (nn >= NOBJ) nn = NOBJ - 1;   // clamp (discarded later)
        float4 bx = reinterpret_cast<const float4*>(boxes)[b * NOBJ + nn];
        ax0[k] = bx.x; ay0[k] = bx.y; ax1[k] = bx.z; ay1[k] = bx.w;
        aarea[k] = (bx.z - bx.x) * (bx.w - bx.y);
    }

    unsigned long long bk[8];
#pragma unroll
    for (int k = 0; k < 8; ++k) bk[k] = 0ull;

#pragma unroll 2
    for (int j = 0; j < 16; ++j) {
        int p = pbase + t + (j << 8);
        float4 pc = gpri[p];
        float hx = pc.z / 2.0f, hy = pc.w / 2.0f;
        float px0 = pc.x - hx, py0 = pc.y - hy;
        float px1 = pc.x + hx, py1 = pc.y + hy;
        float areab = (px1 - px0) * (py1 - py0);
        unsigned inv = 0xFFFFFFFFu - (unsigned)p;
#pragma unroll
        for (int k = 0; k < 8; ++k) {
            float ltx = fmaxf(ax0[k], px0), lty = fmaxf(ay0[k], py0);
            float rbx = fminf(ax1[k], px1), rby = fminf(ay1[k], py1);
            float dx = fmaxf(rbx - ltx, 0.0f);
            float dy = fmaxf(rby - lty, 0.0f);
            float inter = dx * dy;
            float iou = __fdividef(inter, (aarea[k] + areab) - inter);
            unsigned long long key =
                ((unsigned long long)__float_as_uint(iou) << 32) |
                (unsigned long long)inv;
            if (key > bk[k]) bk[k] = key;   // ties: larger inv = smaller p
        }
    }
    __syncthreads();                         // sbest init visible
#pragma unroll
    for (int k = 0; k < 8; ++k) {
        unsigned long long v = bk[k];
        for (int o = 32; o > 0; o >>= 1) {
            unsigned long long other = __shfl_down(v, o, 64);
            if (other > v) v = other;
        }
        if ((t & 63) == 0) atomicMax(&sbest[k], v);
    }
    __syncthreads();
    if (t < 8 && n0 + t < NOBJ)
        bp_part[chunk * BB * NOBJ + b * NOBJ + n0 + t] = sbest[t];
}

// fused: per-prior IoU argmax + forced-prior overwrite + label/L1/CE +
// per-block partial sums. overlap/objfor never touch memory.
__global__ __launch_bounds__(256) void k_main(
    const float* __restrict__ locs, const float* __restrict__ scores,
    const float* __restrict__ boxes, const int* __restrict__ labels,
    const float* __restrict__ priors,
    const unsigned long long* __restrict__ bp_part,
    float* __restrict__ neg, double* __restrict__ pc_conf,
    double* __restrict__ pc_loc, int* __restrict__ pc_npos)
{
#pragma clang fp contract(off)
    const int b   = (int)blockIdx.x >> 6;
    const int p0  = ((int)blockIdx.x & 63) << 8;
    const int t   = (int)threadIdx.x;
    const int p   = p0 + t;
    const int idx = b * PP + p;

    __shared__ float sls[256 * NCLS];
    __shared__ int   spf[NOBJ];              // forced prior per object
    __shared__ double sconf[4], sloc[4];
    __shared__ int    snp[4];

    // stage 256x21 scores tile via coalesced float4 loads
    {
        const float4* gsc = reinterpret_cast<const float4*>(
            scores + (size_t)(b * PP + p0) * NCLS);
        float4* dls = reinterpret_cast<float4*>(sls);
#pragma unroll
        for (int i = 0; i < 6; ++i) {
            int j = i * 256 + t;
            if (j < (256 * NCLS) / 4) dls[j] = gsc[j];
        }
    }
    // reduce the 4 chunk-partials -> forced prior table
    if (t < NOBJ) {
        unsigned long long k0 = bp_part[0 * BB * NOBJ + b * NOBJ + t];
        unsigned long long k1 = bp_part[1 * BB * NOBJ + b * NOBJ + t];
        unsigned long long k2 = bp_part[2 * BB * NOBJ + b * NOBJ + t];
        unsigned long long k3 = bp_part[3 * BB * NOBJ + b * NOBJ + t];
        if (k1 > k0) k0 = k1;
        if (k3 > k2) k2 = k3;
        if (k2 > k0) k0 = k2;
        spf[t] = (int)(0xFFFFFFFFu - (unsigned)(k0 & 0xFFFFFFFFull));
    }
    __syncthreads();

    // per-prior argmax over objects (registers; boxes via uniform s_load)
    const float4* gbox = reinterpret_cast<const float4*>(boxes) + b * NOBJ;
    float4 pc = reinterpret_cast<const float4*>(priors)[p];
    float hx = pc.z / 2.0f, hy = pc.w / 2.0f;
    float px0 = pc.x - hx, py0 = pc.y - hy;
    float px1 = pc.x + hx, py1 = pc.y + hy;
    float areab = (px1 - px0) * (py1 - py0);

    float best = -1.0f; int bestn = 0;
#pragma unroll 10
    for (int n = 0; n < NOBJ; ++n) {
        float4 bx = gbox[n];
        float ltx = fmaxf(bx.x, px0), lty = fmaxf(bx.y, py0);
        float rbx = fminf(bx.z, px1), rby = fminf(bx.w, py1);
        float dx = fmaxf(rbx - ltx, 0.0f);
        float dy = fmaxf(rby - lty, 0.0f);
        float inter = dx * dy;
        float sarea = (bx.z - bx.x) * (bx.w - bx.y);
        float iou = __fdividef(inter, (sarea + areab) - inter);
        if (iou > best) { best = iou; bestn = n; }   // first-max wins (strict >)
    }
    // forced-prior overwrite (ascending n: last wins, matches scatter order)
    bool forced = false;
    for (int n = 0; n < NOBJ; ++n)
        if (spf[n] == p) { bestn = n; forced = true; }
    const float v = forced ? 1.0f : best;

    int lbl = labels[b * NOBJ + bestn];
    if (v < 0.5f) lbl = 0;
    const bool pos = (lbl != 0);

    float locl1 = 0.0f;
    if (pos) {
        float4 bx = gbox[bestn];
        float cx = (bx.x + bx.z) / 2.0f;
        float cy = (bx.y + bx.w) / 2.0f;
        float w  = bx.z - bx.x, h = bx.w - bx.y;
        float gx = (cx - pc.x) / (pc.z / 10.0f);
        float gy = (cy - pc.y) / (pc.w / 10.0f);
        float gw = logf(w / pc.z) * 5.0f;
        float gh = logf(h / pc.w) * 5.0f;
        float4 pl = reinterpret_cast<const float4*>(locs)[idx];
        locl1 = fabsf(pl.x - gx) + fabsf(pl.y - gy) +
                fabsf(pl.z - gw) + fabsf(pl.w - gh);
    }

    // cross-entropy via log-softmax over 21 classes (from LDS)
    float x[NCLS];
    float m = -FLT_MAX;
#pragma unroll
    for (int c = 0; c < NCLS; ++c) { x[c] = sls[t * NCLS + c]; m = fmaxf(m, x[c]); }
    float tgt = 0.0f;
#pragma unroll
    for (int c = 0; c < NCLS; ++c) tgt = (c == lbl) ? x[c] : tgt;
    float s = 0.0f;
#pragma unroll
    for (int c = 0; c < NCLS; ++c) s += expf(x[c] - m);
    float ce = (logf(s) + m) - tgt;

    neg[idx] = pos ? 0.0f : ce;

    // wave reductions -> per-block partials (NO global atomics)
    float cp = pos ? ce : 0.0f;
    unsigned long long bal = __ballot(pos);
    float s1 = cp, s2 = locl1;
    for (int o = 32; o > 0; o >>= 1) {
        s1 += __shfl_down(s1, o, 64);
        s2 += __shfl_down(s2, o, 64);
    }
    if ((t & 63) == 0) {
        int w = t >> 6;
        sconf[w] = (double)s1;
        sloc[w]  = (double)s2;
        snp[w]   = (int)__popcll(bal);
    }
    __syncthreads();
    if (t == 0) {
        pc_conf[blockIdx.x] = sconf[0] + sconf[1] + sconf[2] + sconf[3];
        pc_loc[blockIdx.x]  = sloc[0] + sloc[1] + sloc[2] + sloc[3];
        pc_npos[blockIdx.x] = snp[0] + snp[1] + snp[2] + snp[3];
    }
}

// exact top-K sum via 4x8-bit radix select; values register-resident,
// per-LANE histogram copies, parallel suffix-scan bin selection.
// computes its own n_pos from pc_npos; plain store of hard[b].
__global__ __launch_bounds__(1024) void k_topk(
    const float* __restrict__ neg, const int* __restrict__ pc_npos,
    double* __restrict__ hard)
{
    const int b    = (int)blockIdx.x;
    const int t    = (int)threadIdx.x;
    const int lane = t & 63;
    const int wid  = t >> 6;

    __shared__ unsigned hist[64 * 257];        // per-lane copies, padded
    __shared__ unsigned ssuf[256];
    __shared__ unsigned s_bb, s_above;
    __shared__ float swave[16];
    __shared__ int s_np;

    if (t < 64) {
        int v = pc_npos[b * PBLK + t];
        for (int o = 32; o > 0; o >>= 1) v += __shfl_down(v, o, 64);
        if (t == 0) s_np = v;
    }

    // each thread owns 16 values in registers (one coalesced sweep)
    float v[16];
    {
        const float4* g = reinterpret_cast<const float4*>(neg + (size_t)b * PP);
#pragma unroll
        for (int i = 0; i < 4; ++i) {
            float4 q = g[i * 1024 + t];
            v[i*4+0] = q.x; v[i*4+1] = q.y; v[i*4+2] = q.z; v[i*4+3] = q.w;
        }
    }
    __syncthreads();

    long long K = 3LL * (long long)s_np;
    if (K > PP) K = PP;
    unsigned remaining = (unsigned)K;
    unsigned prefix = 0, mask = 0;
    float mySum = 0.0f;

    for (int shift = 24; shift >= 0; shift -= 8) {
        for (int i = t; i < 64 * 257; i += 1024) hist[i] = 0;
        __syncthreads();
        unsigned* h = hist + lane * 257;
#pragma unroll
        for (int i = 0; i < 16; ++i) {
            unsigned u = __float_as_uint(v[i]);
            if ((u & mask) == prefix) atomicAdd(&h[(u >> shift) & 255u], 1u);
        }
        __syncthreads();
        // combine 64 copies -> own-count in reg + ssuf
        unsigned cnt = 0;
        if (t < 256) {
#pragma unroll
            for (int w = 0; w < 64; ++w) cnt += hist[w * 257 + t];
            ssuf[t] = cnt;
        }
        __syncthreads();
        // inclusive suffix sum over 256 bins (Hillis-Steele)
        for (int off = 1; off < 256; off <<= 1) {
            unsigned add = 0;
            if (t < 256 && t + off < 256) add = ssuf[t + off];
            __syncthreads();
            if (t < 256) ssuf[t] += add;
            __syncthreads();
        }
        if (t < 256) {
            unsigned suf = ssuf[t];
            if (suf >= remaining && suf - cnt < remaining) {
                s_bb = (unsigned)t; s_above = suf - cnt;
            }
        }
        __syncthreads();
        unsigned bb = s_bb;
#pragma unroll
        for (int i = 0; i < 16; ++i) {
            unsigned u = __float_as_uint(v[i]);
            if ((u & mask) == prefix && ((u >> shift) & 255u) > bb)
                mySum += v[i];
        }
        remaining -= s_above;
        prefix |= bb << shift;
        mask   |= 255u << shift;
        __syncthreads();
    }

    float s = mySum;
    for (int o = 32; o > 0; o >>= 1) s += __shfl_down(s, o, 64);
    if ((t & 63) == 0) swave[wid] = s;
    __syncthreads();
    if (t == 0) {
        float tot = 0.0f;
        for (int w = 0; w < 16; ++w) tot += swave[w];
        if (remaining) tot += (float)remaining * __uint_as_float(prefix);
        hard[b] = (double)tot;               // plain store, no atomics
    }
}

__global__ __launch_bounds__(256) void k_final(
    const double* __restrict__ pc_conf, const double* __restrict__ pc_loc,
    const int* __restrict__ pc_npos, const double* __restrict__ hard,
    float* __restrict__ out)
{
    const int t = (int)threadIdx.x;
    __shared__ double sa[4], sb[4], sh[4];
    __shared__ int sn[4];
    double a = 0.0, c = 0.0, h = 0.0; int np = 0;
    for (int i = t; i < NBLK; i += 256) {
        a += pc_conf[i]; c += pc_loc[i]; np += pc_npos[i];
    }
    if (t < BB) h = hard[t];
    for (int o = 32; o > 0; o >>= 1) {
        a += __shfl_down(a, o, 64);
        c += __shfl_down(c, o, 64);
        h += __shfl_down(h, o, 64);
        np += __shfl_down(np, o, 64);
    }
    if ((t & 63) == 0) { int w = t >> 6; sa[w]=a; sb[w]=c; sh[w]=h; sn[w]=np; }
    __syncthreads();
    if (t == 0) {
        double at = sa[0]+sa[1]+sa[2]+sa[3];
        double ct = sb[0]+sb[1]+sb[2]+sb[3];
        double ht = sh[0]+sh[1]+sh[2]+sh[3];
        double npt = (double)(sn[0]+sn[1]+sn[2]+sn[3]);
        out[0] = (float)((at + ht) / npt + ct / (npt * 4.0));
    }
}

extern "C" void kernel_launch(void* const* d_in, const int* in_sizes, int n_in,
                              void* d_out, int out_size, void* d_ws, size_t ws_size,
                              hipStream_t stream) {
    const float* locs   = (const float*)d_in[0];
    const float* scores = (const float*)d_in[1];
    const float* boxes  = (const float*)d_in[2];
    const int*   labels = (const int*)d_in[3];
    const float* priors = (const float*)d_in[4];

    char* ws = (char*)d_ws;
    unsigned long long* bp_part = (unsigned long long*)ws;
    double* pc_conf = (double*)(ws + 51200);
    double* pc_loc  = (double*)(ws + 67584);
    int*    pc_npos = (int*)(ws + 83968);
    double* hard    = (double*)(ws + 92160);
    float*  neg     = (float*)(ws + 131072);
    float*  out     = (float*)d_out;

    hipLaunchKernelGGL(k_bestp, dim3(BB * 28), dim3(256),  0, stream,
                       boxes, priors, bp_part);
    hipLaunchKernelGGL(k_main,  dim3(NBLK),    dim3(256),  0, stream,
                       locs, scores, boxes, labels, priors, bp_part,
                       neg, pc_conf, pc_loc, pc_npos);
    hipLaunchKernelGGL(k_topk,  dim3(BB),      dim3(1024), 0, stream,
                       neg, pc_npos, hard);
    hipLaunchKernelGGL(k_final, dim3(1),       dim3(256),  0, stream,
                       pc_conf, pc_loc, pc_npos, hard, out);
}

// Round 8
// 83.288 us; speedup vs baseline: 2.1084x; 1.0351x over previous
//
#include <hip/hip_runtime.h>
#include <hip/hip_bf16.h>
#include <float.h>

#define BB   32
#define PP   16384
#define NOBJ 50
#define NCLS 21
#define PBLK 64   // blocks of 256 priors per image (P/256)
#define NBLK (BB * PBLK)

// ---------------- workspace layout ----------------
// [0]       u64    bp_part[4][BB*NOBJ]  (51200 B) per-chunk best-prior keys
// [65536]   double pc_conf[NBLK]        (16 KB)
// [81920]   double pc_loc[NBLK]         (16 KB)
// [98304]   int    pc_npos[NBLK]        (8 KB)
// [106496]  double hard[BB]             (256 B)
// [131072]  u64    ovk[BB*PP]           (4 MB)  per-prior (iou<<32)|(49-n)
// [4456448] float  neg[BB*PP]           (2 MB)

// single IoU-grid pass: 8 objects x 4096 priors per block.
// outputs (a) per-object per-chunk best-prior key (plain store, exact) and
// (b) per-prior best-object key via global atomicMax (exact; ties->smaller n)
__global__ __launch_bounds__(256) void k_iou(
    const float* __restrict__ boxes, const float* __restrict__ priors,
    unsigned long long* __restrict__ bp_part,
    unsigned long long* __restrict__ ovk)
{
#pragma clang fp contract(off)
    const int b     = (int)blockIdx.x / 28;
    const int r     = (int)blockIdx.x % 28;
    const int n0    = (r >> 2) * 8;
    const int chunk = r & 3;
    const int pbase = chunk << 12;
    const int t     = (int)threadIdx.x;
    const float4* gpri = reinterpret_cast<const float4*>(priors);

    __shared__ unsigned long long sbest[8];
    if (t < 8) sbest[t] = 0ull;

    float ax0[8], ay0[8], ax1[8], ay1[8], aarea[8];
    unsigned lo[8];
#pragma unroll
    for (int k = 0; k < 8; ++k) {
        int nn = n0 + k; if (nn >= NOBJ) nn = NOBJ - 1;  // clamp: dup of n=49
        float4 bx = reinterpret_cast<const float4*>(boxes)[b * NOBJ + nn];
        ax0[k] = bx.x; ay0[k] = bx.y; ax1[k] = bx.z; ay1[k] = bx.w;
        aarea[k] = (bx.z - bx.x) * (bx.w - bx.y);
        lo[k] = (unsigned)(NOBJ - 1 - nn);               // ties -> smaller n
    }

    unsigned long long bk[8];
#pragma unroll
    for (int k = 0; k < 8; ++k) bk[k] = 0ull;

#pragma unroll 2
    for (int j = 0; j < 16; ++j) {
        int p = pbase + t + (j << 8);
        float4 pc = gpri[p];
        float hx = pc.z / 2.0f, hy = pc.w / 2.0f;
        float px0 = pc.x - hx, py0 = pc.y - hy;
        float px1 = pc.x + hx, py1 = pc.y + hy;
        float areab = (px1 - px0) * (py1 - py0);
        unsigned inv = 0xFFFFFFFFu - (unsigned)p;
        unsigned long long pb = 0ull;
#pragma unroll
        for (int k = 0; k < 8; ++k) {
            float ltx = fmaxf(ax0[k], px0), lty = fmaxf(ay0[k], py0);
            float rbx = fminf(ax1[k], px1), rby = fminf(ay1[k], py1);
            float dx = fmaxf(rbx - ltx, 0.0f);
            float dy = fmaxf(rby - lty, 0.0f);
            float inter = dx * dy;
            float iou = __fdividef(inter, (aarea[k] + areab) - inter);
            unsigned long long hib = (unsigned long long)__float_as_uint(iou) << 32;
            unsigned long long keyo = hib | (unsigned long long)inv;
            if (keyo > bk[k]) bk[k] = keyo;   // per-object: ties -> smaller p
            unsigned long long keyp = hib | (unsigned long long)lo[k];
            if (keyp > pb) pb = keyp;         // per-prior: ties -> smaller n
        }
        atomicMax(&ovk[b * PP + p], pb);      // 7 blocks/prior, fire-and-forget
    }
    __syncthreads();                          // sbest init visible
#pragma unroll
    for (int k = 0; k < 8; ++k) {
        unsigned long long v = bk[k];
        for (int o = 32; o > 0; o >>= 1) {
            unsigned long long other = __shfl_down(v, o, 64);
            if (other > v) v = other;
        }
        if ((t & 63) == 0) atomicMax(&sbest[k], v);
    }
    __syncthreads();
    if (t < 8 && n0 + t < NOBJ)
        bp_part[chunk * BB * NOBJ + b * NOBJ + n0 + t] = sbest[t];
}

// fused: decode per-prior argmax from ovk + forced-prior table + label/L1/CE +
// per-block partial sums. No IoU recompute.
__global__ __launch_bounds__(256) void k_main(
    const float* __restrict__ locs, const float* __restrict__ scores,
    const float* __restrict__ boxes, const int* __restrict__ labels,
    const float* __restrict__ priors,
    const unsigned long long* __restrict__ bp_part,
    const unsigned long long* __restrict__ ovk,
    float* __restrict__ neg, double* __restrict__ pc_conf,
    double* __restrict__ pc_loc, int* __restrict__ pc_npos)
{
#pragma clang fp contract(off)
    const int b   = (int)blockIdx.x >> 6;
    const int p0  = ((int)blockIdx.x & 63) << 8;
    const int t   = (int)threadIdx.x;
    const int p   = p0 + t;
    const int idx = b * PP + p;

    __shared__ float  sls[256 * NCLS];
    __shared__ int    sforce[256];           // local prior -> forcing object
    __shared__ float4 sbox[NOBJ];
    __shared__ int    slab[NOBJ];
    __shared__ double sconf[4], sloc[4];
    __shared__ int    snp[4];

    // stage 256x21 scores tile via coalesced float4 loads
    {
        const float4* gsc = reinterpret_cast<const float4*>(
            scores + (size_t)(b * PP + p0) * NCLS);
        float4* dls = reinterpret_cast<float4*>(sls);
#pragma unroll
        for (int i = 0; i < 6; ++i) {
            int j = i * 256 + t;
            if (j < (256 * NCLS) / 4) dls[j] = gsc[j];
        }
    }
    sforce[t] = -1;
    if (t < NOBJ) {
        sbox[t] = reinterpret_cast<const float4*>(boxes)[b * NOBJ + t];
        slab[t] = labels[b * NOBJ + t];
    }
    __syncthreads();
    if (t < NOBJ) {
        unsigned long long k0 = bp_part[0 * BB * NOBJ + b * NOBJ + t];
        unsigned long long k1 = bp_part[1 * BB * NOBJ + b * NOBJ + t];
        unsigned long long k2 = bp_part[2 * BB * NOBJ + b * NOBJ + t];
        unsigned long long k3 = bp_part[3 * BB * NOBJ + b * NOBJ + t];
        if (k1 > k0) k0 = k1;
        if (k3 > k2) k2 = k3;
        if (k2 > k0) k0 = k2;
        int spf = (int)(0xFFFFFFFFu - (unsigned)(k0 & 0xFFFFFFFFull));
        if (spf >= p0 && spf < p0 + 256)
            atomicMax(&sforce[spf - p0], t);   // max n = last-wins scatter
    }
    __syncthreads();

    // per-prior argmax decoded from the single IoU pass
    unsigned long long key = ovk[idx];
    int   bestn = NOBJ - 1 - (int)((unsigned)key & 63u);
    float v     = __uint_as_float((unsigned)(key >> 32));
    int fn = sforce[t];
    if (fn >= 0) { bestn = fn; v = 1.0f; }

    int lbl = slab[bestn];
    if (v < 0.5f) lbl = 0;
    const bool pos = (lbl != 0);

    float locl1 = 0.0f;
    if (pos) {
        float4 bx = sbox[bestn];
        float4 pc = reinterpret_cast<const float4*>(priors)[p];
        float cx = (bx.x + bx.z) / 2.0f;
        float cy = (bx.y + bx.w) / 2.0f;
        float w  = bx.z - bx.x, h = bx.w - bx.y;
        float gx = (cx - pc.x) / (pc.z / 10.0f);
        float gy = (cy - pc.y) / (pc.w / 10.0f);
        float gw = logf(w / pc.z) * 5.0f;
        float gh = logf(h / pc.w) * 5.0f;
        float4 pl = reinterpret_cast<const float4*>(locs)[idx];
        locl1 = fabsf(pl.x - gx) + fabsf(pl.y - gy) +
                fabsf(pl.z - gw) + fabsf(pl.w - gh);
    }

    // cross-entropy via log-softmax over 21 classes (from LDS)
    float x[NCLS];
    float m = -FLT_MAX;
#pragma unroll
    for (int c = 0; c < NCLS; ++c) { x[c] = sls[t * NCLS + c]; m = fmaxf(m, x[c]); }
    float tgt = sls[t * NCLS + lbl];         // single LDS read, no 21-way select
    float s = 0.0f;
#pragma unroll
    for (int c = 0; c < NCLS; ++c) s += expf(x[c] - m);
    float ce = (logf(s) + m) - tgt;

    neg[idx] = pos ? 0.0f : ce;

    // wave reductions -> per-block partials (NO global atomics)
    float cp = pos ? ce : 0.0f;
    unsigned long long bal = __ballot(pos);
    float s1 = cp, s2 = locl1;
    for (int o = 32; o > 0; o >>= 1) {
        s1 += __shfl_down(s1, o, 64);
        s2 += __shfl_down(s2, o, 64);
    }
    if ((t & 63) == 0) {
        int w = t >> 6;
        sconf[w] = (double)s1;
        sloc[w]  = (double)s2;
        snp[w]   = (int)__popcll(bal);
    }
    __syncthreads();
    if (t == 0) {
        pc_conf[blockIdx.x] = sconf[0] + sconf[1] + sconf[2] + sconf[3];
        pc_loc[blockIdx.x]  = sloc[0] + sloc[1] + sloc[2] + sloc[3];
        pc_npos[blockIdx.x] = snp[0] + snp[1] + snp[2] + snp[3];
    }
}

// exact top-K sum via 4x8-bit radix select; values register-resident,
// per-LANE histogram copies, parallel suffix-scan bin selection.
__global__ __launch_bounds__(1024) void k_topk(
    const float* __restrict__ neg, const int* __restrict__ pc_npos,
    double* __restrict__ hard)
{
    const int b    = (int)blockIdx.x;
    const int t    = (int)threadIdx.x;
    const int lane = t & 63;
    const int wid  = t >> 6;

    __shared__ unsigned hist[64 * 257];        // per-lane copies, padded
    __shared__ unsigned ssuf[256];
    __shared__ unsigned s_bb, s_above;
    __shared__ float swave[16];
    __shared__ int s_np;

    if (t < 64) {
        int v = pc_npos[b * PBLK + t];
        for (int o = 32; o > 0; o >>= 1) v += __shfl_down(v, o, 64);
        if (t == 0) s_np = v;
    }

    float v[16];
    {
        const float4* g = reinterpret_cast<const float4*>(neg + (size_t)b * PP);
#pragma unroll
        for (int i = 0; i < 4; ++i) {
            float4 q = g[i * 1024 + t];
            v[i*4+0] = q.x; v[i*4+1] = q.y; v[i*4+2] = q.z; v[i*4+3] = q.w;
        }
    }
    __syncthreads();

    long long K = 3LL * (long long)s_np;
    if (K > PP) K = PP;
    unsigned remaining = (unsigned)K;
    unsigned prefix = 0, mask = 0;
    float mySum = 0.0f;

    for (int shift = 24; shift >= 0; shift -= 8) {
        for (int i = t; i < 64 * 257; i += 1024) hist[i] = 0;
        __syncthreads();
        unsigned* h = hist + lane * 257;
#pragma unroll
        for (int i = 0; i < 16; ++i) {
            unsigned u = __float_as_uint(v[i]);
            if ((u & mask) == prefix) atomicAdd(&h[(u >> shift) & 255u], 1u);
        }
        __syncthreads();
        unsigned cnt = 0;
        if (t < 256) {
#pragma unroll
            for (int w = 0; w < 64; ++w) cnt += hist[w * 257 + t];
            ssuf[t] = cnt;
        }
        __syncthreads();
        for (int off = 1; off < 256; off <<= 1) {
            unsigned add = 0;
            if (t < 256 && t + off < 256) add = ssuf[t + off];
            __syncthreads();
            if (t < 256) ssuf[t] += add;
            __syncthreads();
        }
        if (t < 256) {
            unsigned suf = ssuf[t];
            if (suf >= remaining && suf - cnt < remaining) {
                s_bb = (unsigned)t; s_above = suf - cnt;
            }
        }
        __syncthreads();
        unsigned bb = s_bb;
#pragma unroll
        for (int i = 0; i < 16; ++i) {
            unsigned u = __float_as_uint(v[i]);
            if ((u & mask) == prefix && ((u >> shift) & 255u) > bb)
                mySum += v[i];
        }
        remaining -= s_above;
        prefix |= bb << shift;
        mask   |= 255u << shift;
        __syncthreads();
    }

    float s = mySum;
    for (int o = 32; o > 0; o >>= 1) s += __shfl_down(s, o, 64);
    if ((t & 63) == 0) swave[wid] = s;
    __syncthreads();
    if (t == 0) {
        float tot = 0.0f;
        for (int w = 0; w < 16; ++w) tot += swave[w];
        if (remaining) tot += (float)remaining * __uint_as_float(prefix);
        hard[b] = (double)tot;               // plain store, no atomics
    }
}

__global__ __launch_bounds__(256) void k_final(
    const double* __restrict__ pc_conf, const double* __restrict__ pc_loc,
    const int* __restrict__ pc_npos, const double* __restrict__ hard,
    float* __restrict__ out)
{
    const int t = (int)threadIdx.x;
    __shared__ double sa[4], sb[4], sh[4];
    __shared__ int sn[4];
    double a = 0.0, c = 0.0, h = 0.0; int np = 0;
    for (int i = t; i < NBLK; i += 256) {
        a += pc_conf[i]; c += pc_loc[i]; np += pc_npos[i];
    }
    if (t < BB) h = hard[t];
    for (int o = 32; o > 0; o >>= 1) {
        a += __shfl_down(a, o, 64);
        c += __shfl_down(c, o, 64);
        h += __shfl_down(h, o, 64);
        np += __shfl_down(np, o, 64);
    }
    if ((t & 63) == 0) { int w = t >> 6; sa[w]=a; sb[w]=c; sh[w]=h; sn[w]=np; }
    __syncthreads();
    if (t == 0) {
        double at = sa[0]+sa[1]+sa[2]+sa[3];
        double ct = sb[0]+sb[1]+sb[2]+sb[3];
        double ht = sh[0]+sh[1]+sh[2]+sh[3];
        double npt = (double)(sn[0]+sn[1]+sn[2]+sn[3]);
        out[0] = (float)((at + ht) / npt + ct / (npt * 4.0));
    }
}

extern "C" void kernel_launch(void* const* d_in, const int* in_sizes, int n_in,
                              void* d_out, int out_size, void* d_ws, size_t ws_size,
                              hipStream_t stream) {
    const float* locs   = (const float*)d_in[0];
    const float* scores = (const float*)d_in[1];
    const float* boxes  = (const float*)d_in[2];
    const int*   labels = (const int*)d_in[3];
    const float* priors = (const float*)d_in[4];

    char* ws = (char*)d_ws;
    unsigned long long* bp_part = (unsigned long long*)ws;
    double* pc_conf = (double*)(ws + 65536);
    double* pc_loc  = (double*)(ws + 81920);
    int*    pc_npos = (int*)(ws + 98304);
    double* hard    = (double*)(ws + 106496);
    unsigned long long* ovk = (unsigned long long*)(ws + 131072);
    float*  neg     = (float*)(ws + 4456448);
    float*  out     = (float*)d_out;

    hipMemsetAsync(ovk, 0, (size_t)BB * PP * 8, stream);
    hipLaunchKernelGGL(k_iou,   dim3(BB * 28), dim3(256),  0, stream,
                       boxes, priors, bp_part, ovk);
    hipLaunchKernelGGL(k_main,  dim3(NBLK),    dim3(256),  0, stream,
                       locs, scores, boxes, labels, priors, bp_part, ovk,
                       neg, pc_conf, pc_loc, pc_npos);
    hipLaunchKernelGGL(k_topk,  dim3(BB),      dim3(1024), 0, stream,
                       neg, pc_npos, hard);
    hipLaunchKernelGGL(k_final, dim3(1),       dim3(256),  0, stream,
                       pc_conf, pc_loc, pc_npos, hard, out);
}

// Round 9
// 80.955 us; speedup vs baseline: 2.1692x; 1.0288x over previous
//
#include <hip/hip_runtime.h>
#include <hip/hip_bf16.h>
#include <float.h>

#define BB   32
#define PP   16384
#define NOBJ 50
#define NCLS 21
#define PBLK 64    // blocks of 256 priors per image in k_main (P/256)
#define NBLK (BB * PBLK)
#define NGRP 7     // object groups of 8 (covers 50 with clamp dups)
#define NCHK 16    // prior chunks of 1024 in k_iou
#define CPRI 1024
#define JPT  4     // priors per thread in k_iou

// ---------------- workspace layout ----------------
// [0]        u64    bp_part[16][BB*NOBJ]   (204800 B) per-chunk best-prior keys
// [262144]   double pc_conf[NBLK]          (16 KB)
// [278528]   double pc_loc[NBLK]           (16 KB)
// [294912]   int    pc_npos[NBLK]          (8 KB)
// [303104]   double hard[BB]               (256 B)
// [327680]   u64    ovp_part[7][BB*PP]     (28.7 MB) per-group best-object keys
// [33554432] float  neg[BB*PP]             (2 MB)

// single IoU-grid pass, no atomics: 8 objects x 1024 priors per block,
// 4 priors x 8 objects per thread, everything register-resident.
// outputs per-chunk best-prior keys and per-group best-object keys (plain stores)
__global__ __launch_bounds__(256) void k_iou(
    const float* __restrict__ boxes, const float* __restrict__ priors,
    unsigned long long* __restrict__ bp_part,
    unsigned long long* __restrict__ ovp_part)
{
#pragma clang fp contract(off)
    const int blk   = (int)blockIdx.x;
    const int b     = blk / (NGRP * NCHK);
    const int rem   = blk % (NGRP * NCHK);
    const int g     = rem / NCHK;
    const int c     = rem % NCHK;
    const int n0    = g * 8;
    const int pbase = c * CPRI;
    const int t     = (int)threadIdx.x;

    __shared__ unsigned long long sbest[8];
    if (t < 8) sbest[t] = 0ull;

    // 8 boxes in registers (uniform -> s_load)
    float ax0[8], ay0[8], ax1[8], ay1[8], aarea[8];
#pragma unroll
    for (int k = 0; k < 8; ++k) {
        int nn = n0 + k; if (nn >= NOBJ) nn = NOBJ - 1;   // clamp: dup of n=49
        float4 bx = reinterpret_cast<const float4*>(boxes)[b * NOBJ + nn];
        ax0[k] = bx.x; ay0[k] = bx.y; ax1[k] = bx.z; ay1[k] = bx.w;
        aarea[k] = (bx.z - bx.x) * (bx.w - bx.y);
    }

    // 4 priors in registers (coalesced)
    float px0[JPT], py0[JPT], px1[JPT], py1[JPT], pab[JPT];
#pragma unroll
    for (int j = 0; j < JPT; ++j) {
        float4 pc = reinterpret_cast<const float4*>(priors)[pbase + t + j * 256];
        float hx = pc.z / 2.0f, hy = pc.w / 2.0f;
        px0[j] = pc.x - hx; py0[j] = pc.y - hy;
        px1[j] = pc.x + hx; py1[j] = pc.y + hy;
        pab[j] = (px1[j] - px0[j]) * (py1[j] - py0[j]);
    }

    float bof[8];  int bop[8];    // best prior per object (this thread)
    float bpf[JPT]; int bpn[JPT]; // best object per prior
#pragma unroll
    for (int k = 0; k < 8; ++k) { bof[k] = -1.0f; bop[k] = 0; }
#pragma unroll
    for (int j = 0; j < JPT; ++j) { bpf[j] = -1.0f; bpn[j] = 0; }

#pragma unroll
    for (int k = 0; k < 8; ++k) {
#pragma unroll
        for (int j = 0; j < JPT; ++j) {
            float ltx = fmaxf(ax0[k], px0[j]), lty = fmaxf(ay0[k], py0[j]);
            float rbx = fminf(ax1[k], px1[j]), rby = fminf(ay1[k], py1[j]);
            float dx = fmaxf(rbx - ltx, 0.0f);
            float dy = fmaxf(rby - lty, 0.0f);
            float inter = dx * dy;
            float iou = __fdividef(inter, (aarea[k] + pab[j]) - inter);
            // ascending j (=ascending p) + strict > : first-max = smallest p
            if (iou > bof[k]) { bof[k] = iou; bop[k] = pbase + t + j * 256; }
            // ascending k (=ascending n) + strict > : first-max = smallest n
            if (iou > bpf[j]) { bpf[j] = iou; bpn[j] = n0 + k; }
        }
    }

    // per-prior partial: plain coalesced u64 store (iou_bits<<32)|(49-n)
#pragma unroll
    for (int j = 0; j < JPT; ++j) {
        unsigned long long key =
            ((unsigned long long)__float_as_uint(bpf[j]) << 32) |
            (unsigned long long)(unsigned)(NOBJ - 1 - bpn[j]);
        ovp_part[((size_t)g * BB + b) * PP + pbase + t + j * 256] = key;
    }

    // per-object: pack (iou_bits<<32)|(~p), wave reduce, LDS merge, plain store
    __syncthreads();                          // sbest init visible
#pragma unroll
    for (int k = 0; k < 8; ++k) {
        unsigned long long v =
            ((unsigned long long)__float_as_uint(bof[k]) << 32) |
            (unsigned long long)(0xFFFFFFFFu - (unsigned)bop[k]);
        for (int o = 32; o > 0; o >>= 1) {
            unsigned long long other = __shfl_down(v, o, 64);
            if (other > v) v = other;
        }
        if ((t & 63) == 0) atomicMax(&sbest[k], v);   // 4 per block: trivial
    }
    __syncthreads();
    if (t < 8 && n0 + t < NOBJ)
        bp_part[(size_t)c * BB * NOBJ + b * NOBJ + n0 + t] = sbest[t];
}

// fused: merge per-prior keys + forced-prior table + label/L1/CE + partials
__global__ __launch_bounds__(256) void k_main(
    const float* __restrict__ locs, const float* __restrict__ scores,
    const float* __restrict__ boxes, const int* __restrict__ labels,
    const float* __restrict__ priors,
    const unsigned long long* __restrict__ bp_part,
    const unsigned long long* __restrict__ ovp_part,
    float* __restrict__ neg, double* __restrict__ pc_conf,
    double* __restrict__ pc_loc, int* __restrict__ pc_npos)
{
#pragma clang fp contract(off)
    const int b   = (int)blockIdx.x >> 6;
    const int p0  = ((int)blockIdx.x & 63) << 8;
    const int t   = (int)threadIdx.x;
    const int p   = p0 + t;
    const int idx = b * PP + p;

    __shared__ float  sls[256 * NCLS];
    __shared__ int    sforce[256];           // local prior -> forcing object
    __shared__ float4 sbox[NOBJ];
    __shared__ int    slab[NOBJ];
    __shared__ double sconf[4], sloc[4];
    __shared__ int    snp[4];

    // stage 256x21 scores tile via coalesced float4 loads
    {
        const float4* gsc = reinterpret_cast<const float4*>(
            scores + (size_t)(b * PP + p0) * NCLS);
        float4* dls = reinterpret_cast<float4*>(sls);
#pragma unroll
        for (int i = 0; i < 6; ++i) {
            int j = i * 256 + t;
            if (j < (256 * NCLS) / 4) dls[j] = gsc[j];
        }
    }
    sforce[t] = -1;
    if (t < NOBJ) {
        sbox[t] = reinterpret_cast<const float4*>(boxes)[b * NOBJ + t];
        slab[t] = labels[b * NOBJ + t];
    }
    __syncthreads();
    if (t < NOBJ) {
        unsigned long long k0 = bp_part[b * NOBJ + t];
#pragma unroll
        for (int cc = 1; cc < NCHK; ++cc) {
            unsigned long long kc = bp_part[(size_t)cc * BB * NOBJ + b * NOBJ + t];
            if (kc > k0) k0 = kc;
        }
        int spf = (int)(0xFFFFFFFFu - (unsigned)(k0 & 0xFFFFFFFFull));
        if (spf >= p0 && spf < p0 + 256)
            atomicMax(&sforce[spf - p0], t);   // max n = last-wins scatter
    }
    __syncthreads();

    // per-prior argmax: merge the 7 group partials (coalesced u64 loads)
    unsigned long long key = ovp_part[(size_t)b * PP + p];
#pragma unroll
    for (int g = 1; g < NGRP; ++g) {
        unsigned long long kg = ovp_part[((size_t)g * BB + b) * PP + p];
        if (kg > key) key = kg;
    }
    int   bestn = NOBJ - 1 - (int)((unsigned)key & 63u);
    float v     = __uint_as_float((unsigned)(key >> 32));
    int fn = sforce[t];
    if (fn >= 0) { bestn = fn; v = 1.0f; }

    int lbl = slab[bestn];
    if (v < 0.5f) lbl = 0;
    const bool pos = (lbl != 0);

    float locl1 = 0.0f;
    if (pos) {
        float4 bx = sbox[bestn];
        float4 pc = reinterpret_cast<const float4*>(priors)[p];
        float cx = (bx.x + bx.z) / 2.0f;
        float cy = (bx.y + bx.w) / 2.0f;
        float w  = bx.z - bx.x, h = bx.w - bx.y;
        float gx = (cx - pc.x) / (pc.z / 10.0f);
        float gy = (cy - pc.y) / (pc.w / 10.0f);
        float gw = logf(w / pc.z) * 5.0f;
        float gh = logf(h / pc.w) * 5.0f;
        float4 pl = reinterpret_cast<const float4*>(locs)[idx];
        locl1 = fabsf(pl.x - gx) + fabsf(pl.y - gy) +
                fabsf(pl.z - gw) + fabsf(pl.w - gh);
    }

    // cross-entropy via log-softmax over 21 classes (from LDS)
    float x[NCLS];
    float m = -FLT_MAX;
#pragma unroll
    for (int c = 0; c < NCLS; ++c) { x[c] = sls[t * NCLS + c]; m = fmaxf(m, x[c]); }
    float tgt = sls[t * NCLS + lbl];
    float s = 0.0f;
#pragma unroll
    for (int c = 0; c < NCLS; ++c) s += expf(x[c] - m);
    float ce = (logf(s) + m) - tgt;

    neg[idx] = pos ? 0.0f : ce;

    // wave reductions -> per-block partials (NO global atomics)
    float cp = pos ? ce : 0.0f;
    unsigned long long bal = __ballot(pos);
    float s1 = cp, s2 = locl1;
    for (int o = 32; o > 0; o >>= 1) {
        s1 += __shfl_down(s1, o, 64);
        s2 += __shfl_down(s2, o, 64);
    }
    if ((t & 63) == 0) {
        int w = t >> 6;
        sconf[w] = (double)s1;
        sloc[w]  = (double)s2;
        snp[w]   = (int)__popcll(bal);
    }
    __syncthreads();
    if (t == 0) {
        pc_conf[blockIdx.x] = sconf[0] + sconf[1] + sconf[2] + sconf[3];
        pc_loc[blockIdx.x]  = sloc[0] + sloc[1] + sloc[2] + sloc[3];
        pc_npos[blockIdx.x] = snp[0] + snp[1] + snp[2] + snp[3];
    }
}

// exact top-K sum via 4x8-bit radix select; values register-resident,
// per-LANE histogram copies, parallel suffix-scan bin selection.
__global__ __launch_bounds__(1024) void k_topk(
    const float* __restrict__ neg, const int* __restrict__ pc_npos,
    double* __restrict__ hard)
{
    const int b    = (int)blockIdx.x;
    const int t    = (int)threadIdx.x;
    const int lane = t & 63;
    const int wid  = t >> 6;

    __shared__ unsigned hist[64 * 257];        // per-lane copies, padded
    __shared__ unsigned ssuf[256];
    __shared__ unsigned s_bb, s_above;
    __shared__ float swave[16];
    __shared__ int s_np;

    if (t < 64) {
        int v = pc_npos[b * PBLK + t];
        for (int o = 32; o > 0; o >>= 1) v += __shfl_down(v, o, 64);
        if (t == 0) s_np = v;
    }

    float v[16];
    {
        const float4* g = reinterpret_cast<const float4*>(neg + (size_t)b * PP);
#pragma unroll
        for (int i = 0; i < 4; ++i) {
            float4 q = g[i * 1024 + t];
            v[i*4+0] = q.x; v[i*4+1] = q.y; v[i*4+2] = q.z; v[i*4+3] = q.w;
        }
    }
    __syncthreads();

    long long K = 3LL * (long long)s_np;
    if (K > PP) K = PP;
    unsigned remaining = (unsigned)K;
    unsigned prefix = 0, mask = 0;
    float mySum = 0.0f;

    for (int shift = 24; shift >= 0; shift -= 8) {
        for (int i = t; i < 64 * 257; i += 1024) hist[i] = 0;
        __syncthreads();
        unsigned* h = hist + lane * 257;
#pragma unroll
        for (int i = 0; i < 16; ++i) {
            unsigned u = __float_as_uint(v[i]);
            if ((u & mask) == prefix) atomicAdd(&h[(u >> shift) & 255u], 1u);
        }
        __syncthreads();
        unsigned cnt = 0;
        if (t < 256) {
#pragma unroll
            for (int w = 0; w < 64; ++w) cnt += hist[w * 257 + t];
            ssuf[t] = cnt;
        }
        __syncthreads();
        for (int off = 1; off < 256; off <<= 1) {
            unsigned add = 0;
            if (t < 256 && t + off < 256) add = ssuf[t + off];
            __syncthreads();
            if (t < 256) ssuf[t] += add;
            __syncthreads();
        }
        if (t < 256) {
            unsigned suf = ssuf[t];
            if (suf >= remaining && suf - cnt < remaining) {
                s_bb = (unsigned)t; s_above = suf - cnt;
            }
        }
        __syncthreads();
        unsigned bb = s_bb;
#pragma unroll
        for (int i = 0; i < 16; ++i) {
            unsigned u = __float_as_uint(v[i]);
            if ((u & mask) == prefix && ((u >> shift) & 255u) > bb)
                mySum += v[i];
        }
        remaining -= s_above;
        prefix |= bb << shift;
        mask   |= 255u << shift;
        __syncthreads();
    }

    float s = mySum;
    for (int o = 32; o > 0; o >>= 1) s += __shfl_down(s, o, 64);
    if ((t & 63) == 0) swave[wid] = s;
    __syncthreads();
    if (t == 0) {
        float tot = 0.0f;
        for (int w = 0; w < 16; ++w) tot += swave[w];
        if (remaining) tot += (float)remaining * __uint_as_float(prefix);
        hard[b] = (double)tot;               // plain store, no atomics
    }
}

__global__ __launch_bounds__(256) void k_final(
    const double* __restrict__ pc_conf, const double* __restrict__ pc_loc,
    const int* __restrict__ pc_npos, const double* __restrict__ hard,
    float* __restrict__ out)
{
    const int t = (int)threadIdx.x;
    __shared__ double sa[4], sb[4], sh[4];
    __shared__ int sn[4];
    double a = 0.0, c = 0.0, h = 0.0; int np = 0;
    for (int i = t; i < NBLK; i += 256) {
        a += pc_conf[i]; c += pc_loc[i]; np += pc_npos[i];
    }
    if (t < BB) h = hard[t];
    for (int o = 32; o > 0; o >>= 1) {
        a += __shfl_down(a, o, 64);
        c += __shfl_down(c, o, 64);
        h += __shfl_down(h, o, 64);
        np += __shfl_down(np, o, 64);
    }
    if ((t & 63) == 0) { int w = t >> 6; sa[w]=a; sb[w]=c; sh[w]=h; sn[w]=np; }
    __syncthreads();
    if (t == 0) {
        double at = sa[0]+sa[1]+sa[2]+sa[3];
        double ct = sb[0]+sb[1]+sb[2]+sb[3];
        double ht = sh[0]+sh[1]+sh[2]+sh[3];
        double npt = (double)(sn[0]+sn[1]+sn[2]+sn[3]);
        out[0] = (float)((at + ht) / npt + ct / (npt * 4.0));
    }
}

extern "C" void kernel_launch(void* const* d_in, const int* in_sizes, int n_in,
                              void* d_out, int out_size, void* d_ws, size_t ws_size,
                              hipStream_t stream) {
    const float* locs   = (const float*)d_in[0];
    const float* scores = (const float*)d_in[1];
    const float* boxes  = (const float*)d_in[2];
    const int*   labels = (const int*)d_in[3];
    const float* priors = (const float*)d_in[4];

    char* ws = (char*)d_ws;
    unsigned long long* bp_part = (unsigned long long*)ws;
    double* pc_conf = (double*)(ws + 262144);
    double* pc_loc  = (double*)(ws + 278528);
    int*    pc_npos = (int*)(ws + 294912);
    double* hard    = (double*)(ws + 303104);
    unsigned long long* ovp_part = (unsigned long long*)(ws + 327680);
    float*  neg     = (float*)(ws + 33554432);
    float*  out     = (float*)d_out;

    hipLaunchKernelGGL(k_iou,   dim3(BB * NGRP * NCHK), dim3(256),  0, stream,
                       boxes, priors, bp_part, ovp_part);
    hipLaunchKernelGGL(k_main,  dim3(NBLK),             dim3(256),  0, stream,
                       locs, scores, boxes, labels, priors, bp_part, ovp_part,
                       neg, pc_conf, pc_loc, pc_npos);
    hipLaunchKernelGGL(k_topk,  dim3(BB),               dim3(1024), 0, stream,
                       neg, pc_npos, hard);
    hipLaunchKernelGGL(k_final, dim3(1),                dim3(256),  0, stream,
                       pc_conf, pc_loc, pc_npos, hard, out);
}